// Round 4
// baseline (707.647 us; speedup 1.0000x reference)
//
#include <hip/hip_runtime.h>
#include <math.h>

// ---------------------------------------------------------------------------
// HybridGNN on MI355X — R4.
// agg v3: 32 rows/block, NO W LDS staging (W read from global, L1/L2-hot).
//         LDS = 27 KB -> ~5 blocks/CU (vs 2 at R3's 72 KB). 4x4 reg tiles.
// attn v3: only t=et row survives to output => view attn computes q/LN/out for
//          1 row, meta attn only at t=et. W from global. 256 thr, shuffle LN.
// Workspace layout identical to R1 (rows of 100 f32).
// ---------------------------------------------------------------------------

#define NBATCH 512
#define TOTALP 1086
#define RPB 32      // rows per agg block
#define XSTR 204    // xs LDS row stride (floats)

struct Seg {
  const float* emb;     // gather mode embedding base (null => dense mode)
  const float* selfp;   // dense self rows [N][100]
  const float* neighp;  // dense neighbor rows [N*r][100]
  const int*   ids_s;   // gather: self id array
  const int*   ids_n;   // gather: neighbor id array
  const float* Ws;      // [100][50]
  const float* Wn;      // [100][50]
  float*       outp;    // out row j at outp + j*ostride
  int ss, so;           // self id per-b stride, offset
  int ns, no;           // neigh id per-b stride, offset
  int estride;          // node stride in emb (elements)
  int ostride;
  int c;                // self rows per batch element
  int r;                // fanout
  int blk_begin;        // prefix in fused BLOCK space
};

struct KArgs { Seg seg[14]; int n; };

__global__ __launch_bounds__(256) void agg_kernel(KArgs P) {
  __shared__ float xsh[RPB * XSTR];     // 26.1 KB  xs[row][0:100]=s, [100:200]=m
  __shared__ int   ids_s_sh[RPB];
  __shared__ int   ids_n_sh[RPB * 9];

  const int blk = blockIdx.x, tid = threadIdx.x;
  int si = 0;
  for (int i = 1; i < P.n; ++i)
    if (blk >= P.seg[i].blk_begin) si = i;
  const Seg sg = P.seg[si];
  const int j0 = (blk - sg.blk_begin) * RPB;
  const int c = sg.c, r = sg.r;

  // ---- ids staging (gather mode) ----
  if (sg.emb) {
    if (tid < RPB) {
      int j = j0 + tid, b = j / c, pos = j - b * c;
      ids_s_sh[tid] = sg.ids_s[(long)b * sg.ss + sg.so + pos];
    }
    for (int u = tid; u < RPB * r; u += 256) {
      int row = u / r, q = u - row * r;
      int j = j0 + row, b = j / c, pos = j - b * c;
      ids_n_sh[u] = sg.ids_n[(long)b * sg.ns + sg.no + pos * r + q];
    }
    __syncthreads();
  }

  // ---- Phase B: gather/load X into LDS ----
  const float rinv = 1.f / (float)r;
  for (int u = tid; u < RPB * 25; u += 256) {
    int row = u / 25, q4 = (u - row * 25) * 4;
    float sx, sy, sz, sw, mx = 0.f, my = 0.f, mz = 0.f, mw = 0.f;
    if (sg.emb) {
      const float4 s4 = *(const float4*)(sg.emb + (long)ids_s_sh[row] * sg.estride + q4);
      sx = s4.x; sy = s4.y; sz = s4.z; sw = s4.w;
      for (int rr = 0; rr < r; ++rr) {
        const float4 t = *(const float4*)(sg.emb + (long)ids_n_sh[row * r + rr] * sg.estride + q4);
        mx += t.x; my += t.y; mz += t.z; mw += t.w;
      }
    } else {
      long j = j0 + row;
      const float4 s4 = *(const float4*)(sg.selfp + j * 100 + q4);
      sx = s4.x; sy = s4.y; sz = s4.z; sw = s4.w;
      for (int rr = 0; rr < r; ++rr) {
        const float4 t = *(const float4*)(sg.neighp + (j * r + rr) * 100 + q4);
        mx += t.x; my += t.y; mz += t.z; mw += t.w;
      }
    }
    float4 sv; sv.x = sx; sv.y = sy; sv.z = sz; sv.w = sw;
    float4 mv; mv.x = mx * rinv; mv.y = my * rinv; mv.z = mz * rinv; mv.w = mw * rinv;
    *(float4*)&xsh[row * XSTR + q4]       = sv;
    *(float4*)&xsh[row * XSTR + 100 + q4] = mv;
  }
  __syncthreads();

  // ---- Phase C: 4 rows x 4 cols register tiles, W streamed from global ----
  // units: 8 row-groups x (2 halves x 13 col-units) = 208 threads.
  // half 0: out[0:50] = relu(s @ Ws); half 1: out[50:100] = relu(m @ Wn).
  if (tid < 208) {
    const int rg = tid / 26, hq = tid - rg * 26;
    const int half = hq / 13, q = hq - half * 13;   // q==12 -> cols 48,49 only
    const int col = 4 * q;
    const float* W = half ? sg.Wn : sg.Ws;
    const float* xb = &xsh[(rg * 4) * XSTR + half * 100];
    float acc[4][4];
#pragma unroll
    for (int i = 0; i < 4; ++i) { acc[i][0] = acc[i][1] = acc[i][2] = acc[i][3] = 0.f; }
    if (q < 12) {
#pragma unroll 2
      for (int e = 0; e < 100; ++e) {
        const float4 wv = *(const float4*)&W[e * 50 + col];
#pragma unroll
        for (int i = 0; i < 4; ++i) {
          const float a = xb[i * XSTR + e];
          acc[i][0] = fmaf(a, wv.x, acc[i][0]);
          acc[i][1] = fmaf(a, wv.y, acc[i][1]);
          acc[i][2] = fmaf(a, wv.z, acc[i][2]);
          acc[i][3] = fmaf(a, wv.w, acc[i][3]);
        }
      }
    } else {
#pragma unroll 2
      for (int e = 0; e < 100; ++e) {
        const float2 wv = *(const float2*)&W[e * 50 + 48];
#pragma unroll
        for (int i = 0; i < 4; ++i) {
          const float a = xb[i * XSTR + e];
          acc[i][0] = fmaf(a, wv.x, acc[i][0]);
          acc[i][1] = fmaf(a, wv.y, acc[i][1]);
        }
      }
    }
    const int ocol = half * 50 + col;
    for (int i = 0; i < 4; ++i) {
      const long j = j0 + rg * 4 + i;
      float* op = sg.outp + j * (long)sg.ostride + ocol;
      if (q < 12) {
        float4 o;
        o.x = fmaxf(acc[i][0], 0.f); o.y = fmaxf(acc[i][1], 0.f);
        o.z = fmaxf(acc[i][2], 0.f); o.w = fmaxf(acc[i][3], 0.f);
        *(float4*)op = o;
      } else {
        float2 o;
        o.x = fmaxf(acc[i][0], 0.f); o.y = fmaxf(acc[i][1], 0.f);
        *(float2*)op = o;
      }
    }
  }
}

// ---------------------------------------------------------------------------
__device__ __forceinline__ float wave_sum_bcast(float p) {
#pragma unroll
  for (int off = 32; off; off >>= 1) p += __shfl_down(p, off);
  return __shfl(p, 0);
}

// One block per batch row b, 256 threads. Only the t=et slice is needed at
// the output, so: view attn computes LN/q/out for row et only (k,v for both
// t); meta attn runs on the 3 view rows at t=et; pool/reflect on 100 floats.
__global__ __launch_bounds__(256) void attn_final_kernel(
    const float* __restrict__ spec, const float* __restrict__ rview,
    const int* __restrict__ nodeids, const int* __restrict__ edgetype,
    const float* __restrict__ base_embed, const float* __restrict__ reflect,
    const float* __restrict__ vWq, const float* __restrict__ vWk,
    const float* __restrict__ vWv, const float* __restrict__ vWf,
    const float* __restrict__ vg, const float* __restrict__ vb,
    const float* __restrict__ mWq, const float* __restrict__ mWk,
    const float* __restrict__ mWv, const float* __restrict__ mWf,
    const float* __restrict__ mg, const float* __restrict__ mb,
    float* __restrict__ out)
{
  __shared__ float xs[600], lnb[300], qq[300], kk[300], vv[300], ot[300];
  __shared__ float sc[9], musd[6], pooled[100], r200[200], nrmv[1];
  const int b = blockIdx.x, tid = threadIdx.x;
  const int et = edgetype[NBATCH + b];    // edgetype[1][b]
  const int nid = nodeids[b];

  // xs[v*200 + t*100 + d]; views: 0=spec0, 1=spec1, 2=rview (dup for both t)
  for (int o = tid; o < 600; o += 256) {
    int v = o / 200, rem = o - v * 200;
    xs[o] = (v < 2) ? spec[(long)b * 400 + o] : rview[(long)b * 100 + (rem % 100)];
  }
  __syncthreads();

  // ---- view attention (seq over t, n=2), query/output row t=et only ----
  for (int v = 0; v < 3; ++v) {
    float* xq = xs + v * 200 + et * 100;
    if (tid < 64) {
      float p = (tid < 50) ? xq[tid] + xq[tid + 50] : 0.f;
      p = wave_sum_bcast(p);
      float mu = p * 0.01f, vr = 0.f;
      if (tid < 50) { float a = xq[tid] - mu, c2 = xq[tid + 50] - mu; vr = a * a + c2 * c2; }
      vr = wave_sum_bcast(vr);
      if (tid == 0) { musd[0] = mu; musd[1] = rsqrtf(vr * 0.01f + 1e-6f); }
    }
    __syncthreads();
    if (tid < 100) lnb[tid] = (xq[tid] - musd[0]) * musd[1] * vg[tid] + vb[tid];
    __syncthreads();
    // outputs: o<100: q col (row et); 100..299: k rows t0/t1; 300..499: v rows
    for (int o = tid; o < 500; o += 256) {
      const int m = o / 100, d = o - m * 100;
      const float* xr; const float* W; float* dst;
      if (m == 0)      { xr = lnb;                          W = vWq; dst = qq; }
      else if (m <= 2) { xr = xs + v * 200 + (m - 1) * 100; W = vWk; dst = kk + (m - 1) * 100; }
      else             { xr = xs + v * 200 + (m - 3) * 100; W = vWv; dst = vv + (m - 3) * 100; }
      float a = 0.f;
      for (int e = 0; e < 100; ++e) a = fmaf(xr[e], W[e * 100 + d], a);
      dst[d] = a;
    }
    __syncthreads();
    if (tid < 2) {
      float s = 0.f;
      for (int d = 0; d < 100; ++d) s = fmaf(qq[d], kk[tid * 100 + d], s);
      sc[tid] = s * 0.1f;
    }
    __syncthreads();
    if (tid == 0) {
      float mx = fmaxf(sc[0], sc[1]);
      float e0 = __expf(sc[0] - mx), e1 = __expf(sc[1] - mx);
      float inv = 1.f / (e0 + e1);
      sc[0] = e0 * inv; sc[1] = e1 * inv;
    }
    __syncthreads();
    if (tid < 100) ot[tid] = sc[0] * vv[tid] + sc[1] * vv[100 + tid];
    __syncthreads();
    if (tid < 100) {
      float a = 0.f;
      for (int e = 0; e < 100; ++e) a = fmaf(ot[e], vWf[e * 100 + tid], a);
      xq[tid] += a;   // residual; only this (v, t=et) row is consumed later
    }
    __syncthreads();
  }

  // ---- meta attention (seq over views, n=3) at t=et ----
  {
    const int w = tid >> 6, l = tid & 63;
    if (w < 3) {
      const float* xr = xs + w * 200 + et * 100;
      float p = (l < 50) ? xr[l] + xr[l + 50] : 0.f;
      p = wave_sum_bcast(p);
      float mu = p * 0.01f, vr = 0.f;
      if (l < 50) { float a = xr[l] - mu, c2 = xr[l + 50] - mu; vr = a * a + c2 * c2; }
      vr = wave_sum_bcast(vr);
      if (l == 0) { musd[w * 2] = mu; musd[w * 2 + 1] = rsqrtf(vr * 0.01f + 1e-6f); }
    }
    __syncthreads();
    for (int o = tid; o < 300; o += 256) {
      int i = o / 100, d = o - i * 100;
      lnb[o] = (xs[i * 200 + et * 100 + d] - musd[i * 2]) * musd[i * 2 + 1] * mg[d] + mb[d];
    }
    __syncthreads();
    for (int o = tid; o < 900; o += 256) {
      const int m = o / 300, rr = (o - m * 300) / 100, d = o - m * 300 - rr * 100;
      const float* xr = (m == 0) ? (lnb + rr * 100) : (xs + rr * 200 + et * 100);
      const float* W  = (m == 0) ? mWq : (m == 1 ? mWk : mWv);
      float a = 0.f;
      for (int e = 0; e < 100; ++e) a = fmaf(xr[e], W[e * 100 + d], a);
      float* dst = (m == 0) ? qq : (m == 1 ? kk : vv);
      dst[rr * 100 + d] = a;
    }
    __syncthreads();
    if (tid < 9) {
      int i = tid / 3, u = tid - i * 3;
      float s = 0.f;
      for (int d = 0; d < 100; ++d) s = fmaf(qq[i * 100 + d], kk[u * 100 + d], s);
      sc[tid] = s * 0.1f;
    }
    __syncthreads();
    if (tid < 3) {
      float mx = fmaxf(sc[tid * 3], fmaxf(sc[tid * 3 + 1], sc[tid * 3 + 2]));
      float e0 = __expf(sc[tid * 3] - mx), e1 = __expf(sc[tid * 3 + 1] - mx),
            e2 = __expf(sc[tid * 3 + 2] - mx);
      float inv = 1.f / (e0 + e1 + e2);
      sc[tid * 3] = e0 * inv; sc[tid * 3 + 1] = e1 * inv; sc[tid * 3 + 2] = e2 * inv;
    }
    __syncthreads();
    for (int o = tid; o < 300; o += 256) {
      int i = o / 100, d = o - i * 100;
      ot[o] = sc[i * 3] * vv[d] + sc[i * 3 + 1] * vv[100 + d] + sc[i * 3 + 2] * vv[200 + d];
    }
    __syncthreads();
    for (int o = tid; o < 300; o += 256) {
      int i = o / 100, d = o - i * 100;
      float a = 0.f;
      for (int e = 0; e < 100; ++e) a = fmaf(ot[i * 100 + e], mWf[e * 100 + d], a);
      xs[i * 200 + et * 100 + d] += a;   // residual
    }
    __syncthreads();
  }

  // ---- pool over views (t=et slice), reflect, residual, L2 norm ----
  if (tid < 100)
    pooled[tid] = (xs[et * 100 + tid] + xs[200 + et * 100 + tid] +
                   xs[400 + et * 100 + tid]) * (1.f / 3.f);
  __syncthreads();
  if (tid < 200) {
    float a = base_embed[(long)nid * 200 + tid];
    const float* rf = reflect + (long)et * 20000 + tid;   // reflect[et][d][o]
    for (int d = 0; d < 100; ++d) a = fmaf(pooled[d], rf[d * 200], a);
    r200[tid] = a;
  }
  __syncthreads();
  if (tid < 64) {
    float p = r200[tid] * r200[tid] + r200[tid + 64] * r200[tid + 64]
            + r200[tid + 128] * r200[tid + 128];
    if (tid < 8) p += r200[tid + 192] * r200[tid + 192];
    p = wave_sum_bcast(p);
    if (tid == 0) nrmv[0] = 1.f / fmaxf(sqrtf(p), 1e-12f);
  }
  __syncthreads();
  if (tid < 200) out[(long)b * 200 + tid] = r200[tid] * nrmv[0];
}

// ---------------------------------------------------------------------------
extern "C" void kernel_launch(void* const* d_in, const int* in_sizes, int n_in,
                              void* d_out, int out_size, void* d_ws, size_t ws_size,
                              hipStream_t stream) {
  (void)in_sizes; (void)n_in; (void)out_size; (void)ws_size;
  const int*   nodeids          = (const int*)d_in[0];
  const int*   edgetype         = (const int*)d_in[1];
  const int*   neighbors        = (const int*)d_in[2];
  const int*   random_neighbors = (const int*)d_in[3];
  const float* base_embed       = (const float*)d_in[4];
  const float* type_embed       = (const float*)d_in[5];
  const float* rw_embed         = (const float*)d_in[6];
  const float* reflect          = (const float*)d_in[7];
  const float* agg0_self        = (const float*)d_in[8];
  const float* agg0_neigh       = (const float*)d_in[9];
  const float* agg1_self        = (const float*)d_in[10];
  const float* agg1_neigh       = (const float*)d_in[11];
  const float* rand_self        = (const float*)d_in[12];
  const float* rand_neigh       = (const float*)d_in[13];
  const float* vWq = (const float*)d_in[14];
  const float* vWk = (const float*)d_in[15];
  const float* vWv = (const float*)d_in[16];
  const float* vWf = (const float*)d_in[17];
  const float* vg  = (const float*)d_in[18];
  const float* vb  = (const float*)d_in[19];
  const float* mWq = (const float*)d_in[20];
  const float* mWk = (const float*)d_in[21];
  const float* mWv = (const float*)d_in[22];
  const float* mWf = (const float*)d_in[23];
  const float* mg  = (const float*)d_in[24];
  const float* mb  = (const float*)d_in[25];

  float* ws = (float*)d_ws;
  const long S1r = 147L * NBATCH;                 // schema1 rows per t
  auto rp = [&](long rows) { return ws + rows * 100; };
  float* spec_f  = ws + 306L * NBATCH * 100;      // [B][2][2][100]
  float* rview_f = spec_f + (long)NBATCH * 400;   // [B][100]

  const int  OFF1[4] = {18, 21, 36, 141};
  const int  FAN1[4] = {3, 5, 7, 9};
  const int  C1[4]   = {1, 3, 15, 105};
  const long CUM1[4]  = {0, 1, 4, 19};
  const long CUM1b[3] = {0, 1, 4};

  KArgs A; long acc = 0;   // acc in BLOCKS (32 rows each)
  auto addg = [&](const float* emb, int estride,
                  const int* isrc, int ss, int so, int c,
                  const int* insrc, int nstr, int no, int r,
                  const float* Ws, const float* Wn, float* outp, int ostride) {
    Seg& s = A.seg[A.n++];
    s.emb = emb; s.selfp = nullptr; s.neighp = nullptr;
    s.ids_s = isrc; s.ids_n = insrc;
    s.Ws = Ws; s.Wn = Wn; s.outp = outp;
    s.ss = ss; s.so = so; s.ns = nstr; s.no = no;
    s.estride = estride; s.ostride = ostride;
    s.c = c; s.r = r; s.blk_begin = (int)acc;
    acc += (long)c * NBATCH / RPB;
  };
  auto addd = [&](const float* selfp, const float* neighp, int c, int r,
                  const float* Ws, const float* Wn, float* outp, int ostride) {
    Seg& s = A.seg[A.n++];
    s.emb = nullptr; s.selfp = selfp; s.neighp = neighp;
    s.ids_s = nullptr; s.ids_n = nullptr;
    s.Ws = Ws; s.Wn = Wn; s.outp = outp;
    s.ss = 0; s.so = 0; s.ns = 0; s.no = 0; s.estride = 0; s.ostride = ostride;
    s.c = c; s.r = r; s.blk_begin = (int)acc;
    acc += (long)c * NBATCH / RPB;
  };

  // ---- launch 0: all level-0 (gather) pairs ----
  A.n = 0; acc = 0;
  for (int t = 0; t < 2; ++t)
    for (int k = 0; k < 4; ++k) {
      const float* emb = type_embed + (t * 2 + 1) * 100;
      if (k == 0)
        addg(emb, 400, nodeids, 1, 0, 1,
             neighbors, 2 * TOTALP, t * TOTALP + OFF1[k], FAN1[k],
             agg1_self, agg1_neigh, rp(t * S1r + CUM1[k] * NBATCH), 100);
      else
        addg(emb, 400, neighbors, 2 * TOTALP, t * TOTALP + OFF1[k - 1], C1[k],
             neighbors, 2 * TOTALP, t * TOTALP + OFF1[k], FAN1[k],
             agg1_self, agg1_neigh, rp(t * S1r + CUM1[k] * NBATCH), 100);
    }
  for (int t = 0; t < 2; ++t)
    for (int k = 0; k < 2; ++k) {
      const float* emb = type_embed + (t * 2 + 0) * 100;
      long obase = 294L * NBATCH + (long)t * 4 * NBATCH + (k == 0 ? 0 : 1) * NBATCH;
      if (k == 0)
        addg(emb, 400, nodeids, 1, 0, 1,
             neighbors, 2 * TOTALP, t * TOTALP + 0, 3,
             agg0_self, agg0_neigh, rp(obase), 100);
      else
        addg(emb, 400, neighbors, 2 * TOTALP, t * TOTALP + 0, 3,
             neighbors, 2 * TOTALP, t * TOTALP + 3, 5,
             agg0_self, agg0_neigh, rp(obase), 100);
    }
  for (int k = 0; k < 2; ++k) {
    long obase = 302L * NBATCH + (k == 0 ? 0 : 1) * NBATCH;
    if (k == 0)
      addg(rw_embed, 100, nodeids, 1, 0, 1,
           random_neighbors, 18, 0, 3, rand_self, rand_neigh, rp(obase), 100);
    else
      addg(rw_embed, 100, random_neighbors, 18, 0, 3,
           random_neighbors, 18, 3, 5, rand_self, rand_neigh, rp(obase), 100);
  }
  agg_kernel<<<dim3((unsigned)acc), dim3(256), 0, stream>>>(A);

  // ---- launch 1: schema1 L1, schema0 L1 (final), random L1 (final) ----
  A.n = 0; acc = 0;
  for (int t = 0; t < 2; ++t)
    for (int k = 0; k < 3; ++k)
      addd(rp(t * S1r + CUM1[k] * NBATCH), rp(t * S1r + CUM1[k + 1] * NBATCH),
           C1[k], FAN1[k], agg1_self + 5000, agg1_neigh + 5000,
           rp(t * S1r + 124L * NBATCH + CUM1b[k] * NBATCH), 100);
  for (int t = 0; t < 2; ++t)
    addd(rp(294L * NBATCH + (long)t * 4 * NBATCH),
         rp(294L * NBATCH + (long)t * 4 * NBATCH + NBATCH),
         1, 3, agg0_self + 5000, agg0_neigh + 5000, spec_f + t * 100, 400);
  addd(rp(302L * NBATCH), rp(303L * NBATCH), 1, 3,
       rand_self + 5000, rand_neigh + 5000, rview_f, 100);
  agg_kernel<<<dim3((unsigned)acc), dim3(256), 0, stream>>>(A);

  // ---- launch 2: schema1 L2 ----
  A.n = 0; acc = 0;
  for (int t = 0; t < 2; ++t)
    for (int k = 0; k < 2; ++k)
      addd(rp(t * S1r + 124L * NBATCH + CUM1b[k] * NBATCH),
           rp(t * S1r + 124L * NBATCH + CUM1b[k + 1] * NBATCH),
           C1[k], FAN1[k], agg1_self + 10000, agg1_neigh + 10000,
           rp(t * S1r + 143L * NBATCH + (k == 0 ? 0 : 1) * NBATCH), 100);
  agg_kernel<<<dim3((unsigned)acc), dim3(256), 0, stream>>>(A);

  // ---- launch 3: schema1 L3 (final -> spec view 1) ----
  A.n = 0; acc = 0;
  for (int t = 0; t < 2; ++t)
    addd(rp(t * S1r + 143L * NBATCH), rp(t * S1r + 144L * NBATCH),
         1, 3, agg1_self + 15000, agg1_neigh + 15000,
         spec_f + 200 + t * 100, 400);
  agg_kernel<<<dim3((unsigned)acc), dim3(256), 0, stream>>>(A);

  // ---- launch 4: attention + epilogue ----
  attn_final_kernel<<<dim3(NBATCH), dim3(256), 0, stream>>>(
      spec_f, rview_f, nodeids, edgetype, base_embed, reflect,
      vWq, vWk, vWv, vWf, vg, vb, mWq, mWk, mWv, mWf, mg, mb,
      (float*)d_out);
}